// Round 9
// baseline (139.513 us; speedup 1.0000x reference)
//
#include <hip/hip_runtime.h>
#include <math.h>

// Problem constants
#define NN 256
#define KK 512
#define JJ 6
#define BB 8
#define MPTS 100000
#define NBINS (KK * KK)
// K/(2*pi)
#define KF_SCALE 81.48733086305615f

typedef _Float16 h8 __attribute__((ext_vector_type(8)));
typedef _Float16 h2 __attribute__((ext_vector_type(2)));

// ---------- device helpers ----------

// Abramowitz & Stegun 9.8.1 / 9.8.2 modified Bessel I0, float
__device__ __forceinline__ float i0f_dev(float x) {
    float ax = fabsf(x);
    if (ax < 3.75f) {
        float t = x / 3.75f; t *= t;
        return 1.0f + t*(3.5156229f + t*(3.0899424f + t*(1.2067492f +
               t*(0.2659732f + t*(0.0360768f + t*0.0045813f)))));
    } else {
        float t = 3.75f / ax;
        return (expf(ax) * rsqrtf(ax)) *
               (0.39894228f + t*(0.01328592f + t*(0.00225319f + t*(-0.00157565f +
                t*(0.00916281f + t*(-0.02057706f + t*(0.02635537f +
                t*(-0.01647633f + t*0.00392377f))))))));
    }
}

__device__ __forceinline__ float kbf(float t, float beta, float inv_i0b) {
    float u = t * (1.0f / 3.0f);       // 2*t/J, J=6
    float q = fmaxf(1.0f - u * u, 0.0f);
    return i0f_dev(beta * sqrtf(q)) * inv_i0b;
}

// inclusive wave scan (64 lanes)
__device__ __forceinline__ int wave_scan(int x, int lane) {
#pragma unroll
    for (int off = 1; off < 64; off <<= 1) {
        int y = __shfl_up(x, off, 64);
        if (lane >= off) x += y;
    }
    return x;
}

// Build sPref[0..512] = exclusive row-prefix of btot[512] (sPref[512]=MPTS).
// Runs on wave 0 of the block (threads 0..63); caller must __syncthreads after.
__device__ __forceinline__ void build_row_prefix(const int* __restrict__ btot,
                                                 int* sPref, int t)
{
    if (t < 64) {
        int carry = 0;
        if (t == 0) sPref[0] = 0;
#pragma unroll
        for (int k = 0; k < 8; ++k) {
            int x = btot[k * 64 + t];
            int incl = wave_scan(x, t);
            sPref[k * 64 + t + 1] = incl + carry;
            carry += __shfl(incl, 63, 64);
        }
    }
}

// KB weight via 1024-entry LUT over t in [-3,3], linear interp (err ~4e-4)
__device__ __forceinline__ float kb_lut(const float* __restrict__ sT, float t) {
    float u = (t + 3.0f) * (1023.0f / 6.0f);
    int i = (int)u;
    i = min(i, 1022);
    float f = u - (float)i;
    float a = sT[i];
    return a + f * (sT[i + 1] - sT[i]);
}

// twiddle from 256-entry half-circle table: e^{+i*2*pi*idx/512}, idx in [0,512)
__device__ __forceinline__ void tw_lookup(const float* __restrict__ twc,
                                          const float* __restrict__ tws,
                                          int idx, float& wr, float& wi) {
    float sg = (idx & 256) ? -1.0f : 1.0f;
    int ib = idx & 255;
    wr = sg * twc[ib];
    wi = sg * tws[ib];
}

// ---------- stage bodies ----------

// fill one point's record into its CSR slot, split into two 32B arrays:
// recW[p] = bytes [0,32) of the old 64B record (12B w0, 12B w1, bin1, pad)
// recY[p] = bytes [32,64)                     (yv: 8 batches f16 r,i)
// Byte offsets within each half are unchanged vs the old layout.
__device__ __forceinline__ void fill_point(
    const float2* __restrict__ uv2,
    const float* __restrict__ y_real, const float* __restrict__ y_imag,
    const float* __restrict__ weights, const int* __restrict__ offsets,
    const int* sPref,
    int* counts, char* recW, char* recY, const float* sT, int m)
{
    float2 u = uv2[m];
    float kf0 = u.x * KF_SCALE;
    float kf1 = u.y * KF_SCALE;
    float f0 = floorf(kf0), f1 = floorf(kf1);
    float fr0 = kf0 - f0, fr1 = kf1 - f1;
    int b0r = (int)f0 & (KK - 1);
    int b1c = (int)f1 & (KK - 1);
    int bin = (b0r << 9) | b1c;
    int old = atomicSub(&counts[bin], 1);
    int slot = sPref[b0r] + offsets[bin] + old - 1;

    _Float16 hw[12];
#pragma unroll
    for (int j = 0; j < JJ; ++j) {
        hw[j]     = (_Float16)kb_lut(sT, (float)(j - 2) - fr0);
        hw[6 + j] = (_Float16)kb_lut(sT, (float)(j - 2) - fr1);
    }

    float4 c0v, c1v;
    _Float16* p0 = (_Float16*)&c0v;
    _Float16* p1 = (_Float16*)&c1v;
#pragma unroll
    for (int j = 0; j < 8; ++j) p0[j] = hw[j];        // w0[0..5], w1[0..1]
#pragma unroll
    for (int j = 0; j < 4; ++j) p1[j] = hw[8 + j];    // w1[2..5]
    ((int*)&c1v)[2] = b1c;
    ((int*)&c1v)[3] = 0;

    float wm = weights[m];
    h8 ha, hb;
#pragma unroll
    for (int b = 0; b < 4; ++b) {
        ha[2 * b]     = (_Float16)(y_real[b * MPTS + m] * wm);
        ha[2 * b + 1] = (_Float16)(y_imag[b * MPTS + m] * wm);
        hb[2 * b]     = (_Float16)(y_real[(b + 4) * MPTS + m] * wm);
        hb[2 * b + 1] = (_Float16)(y_imag[(b + 4) * MPTS + m] * wm);
    }

    float4* dW = (float4*)(recW + (size_t)slot * 32);
    dW[0] = c0v;
    dW[1] = c1v;
    float4* dY = (float4*)(recY + (size_t)slot * 32);
    dY[0] = *(float4*)&ha;
    dY[1] = *(float4*)&hb;
}

// ---------- per-wave 512-pt FFT: 8(reg) x 64(lanes via shfl), sign +i ----------
// All twiddles from the 256-entry LDS table (half circle + sign flip).
__device__ __forceinline__ void wave_fft512(float xr[8], float xi[8], int lane,
                                            const float* __restrict__ twc,
                                            const float* __restrict__ tws)
{
    float a0r = xr[0]+xr[4], a0i = xi[0]+xi[4];
    float a4r = xr[0]-xr[4], a4i = xi[0]-xi[4];
    float a2r = xr[2]+xr[6], a2i = xi[2]+xi[6];
    float a6r = xr[2]-xr[6], a6i = xi[2]-xi[6];
    float a1r = xr[1]+xr[5], a1i = xi[1]+xi[5];
    float a5r = xr[1]-xr[5], a5i = xi[1]-xi[5];
    float a3r = xr[3]+xr[7], a3i = xi[3]+xi[7];
    float a7r = xr[3]-xr[7], a7i = xi[3]-xi[7];
    float b0r = a0r+a2r, b0i = a0i+a2i;
    float b2r = a0r-a2r, b2i = a0i-a2i;
    float b4r = a4r-a6i, b4i = a4i+a6r;    // a4 + i*a6
    float b6r = a4r+a6i, b6i = a4i-a6r;    // a4 - i*a6
    float b1r = a1r+a3r, b1i = a1i+a3i;
    float b3r = a1r-a3r, b3i = a1i-a3i;
    float b5r = a5r-a7i, b5i = a5i+a7r;
    float b7r = a5r+a7i, b7i = a5i-a7r;
    const float S2 = 0.70710678118654752f;
    float w5r = S2*(b5r-b5i), w5i = S2*(b5r+b5i);     // W8^1 * b5
    float w7r = -S2*(b7r+b7i), w7i = S2*(b7r-b7i);    // W8^3 * b7
    float y1r = b4r+w5r, y1i = b4i+w5i;
    float y5r = b4r-w5r, y5i = b4i-w5i;
    float y2r = b2r-b3i, y2i = b2i+b3r;    // b2 + i*b3
    float y6r = b2r+b3i, y6i = b2i-b3r;
    float y3r = b6r+w7r, y3i = b6i+w7i;
    float y7r = b6r-w7r, y7i = b6i-w7i;

    int p = __brev((unsigned)lane) >> 26;
    xr[0] = b0r+b1r; xi[0] = b0i+b1i;
    {
        float wr, wi;
        tw_lookup(twc, tws, p,     wr, wi); xr[1] = y1r*wr - y1i*wi; xi[1] = y1i*wr + y1r*wi;
        tw_lookup(twc, tws, p * 2, wr, wi); xr[2] = y2r*wr - y2i*wi; xi[2] = y2i*wr + y2r*wi;
        tw_lookup(twc, tws, p * 3, wr, wi); xr[3] = y3r*wr - y3i*wi; xi[3] = y3i*wr + y3r*wi;
        float y4r = b0r-b1r, y4i = b0i-b1i;
        tw_lookup(twc, tws, p * 4, wr, wi); xr[4] = y4r*wr - y4i*wi; xi[4] = y4i*wr + y4r*wi;
        tw_lookup(twc, tws, p * 5, wr, wi); xr[5] = y5r*wr - y5i*wi; xi[5] = y5i*wr + y5r*wi;
        tw_lookup(twc, tws, p * 6, wr, wi); xr[6] = y6r*wr - y6i*wi; xi[6] = y6i*wr + y6r*wi;
        tw_lookup(twc, tws, p * 7, wr, wi); xr[7] = y7r*wr - y7i*wi; xi[7] = y7i*wr + y7r*wi;
    }

#pragma unroll
    for (int t = 0; t < 6; ++t) {
        int m = 1 << t;
        int j = lane & (m - 1);
        int ti = j << (8 - t);                 // pi*j/m in 512-root table units
        float wc = twc[ti], wsn = tws[ti];
        bool hi = (lane & m) != 0;
#pragma unroll
        for (int d = 0; d < 8; ++d) {
            float pR = __shfl_xor(xr[d], m, 64);
            float pI = __shfl_xor(xi[d], m, 64);
            float bR = hi ? xr[d] : pR;
            float bI = hi ? xi[d] : pI;
            float aR = hi ? pR : xr[d];
            float aI = hi ? pI : xi[d];
            float wbR = wc * bR - wsn * bI;
            float wbI = wc * bI + wsn * bR;
            xr[d] = hi ? aR - wbR : aR + wbR;
            xi[d] = hi ? aI - wbI : aI + wbI;
        }
    }
}

// ---------- per-wave 256-pt FFT: 4(reg) x 64(lanes), sign +i ----------
__device__ __forceinline__ void wave_fft256(float xr[4], float xi[4], int lane,
                                            const float* __restrict__ twc,
                                            const float* __restrict__ tws)
{
    float t0r = xr[0]+xr[2], t0i = xi[0]+xi[2];
    float t1r = xr[0]-xr[2], t1i = xi[0]-xi[2];
    float t2r = xr[1]+xr[3], t2i = xi[1]+xi[3];
    float t3r = xr[1]-xr[3], t3i = xi[1]-xi[3];
    float y1r = t1r-t3i, y1i = t1i+t3r;    // t1 + i*t3
    float y3r = t1r+t3i, y3i = t1i-t3r;    // t1 - i*t3

    int p2 = (__brev((unsigned)lane) >> 26) << 1;   // 2*p, table units
    xr[0] = t0r+t2r; xi[0] = t0i+t2i;
    {
        float wr, wi;
        tw_lookup(twc, tws, p2,     wr, wi); xr[1] = y1r*wr - y1i*wi; xi[1] = y1i*wr + y1r*wi;
        float y2r = t0r-t2r, y2i = t0i-t2i;
        tw_lookup(twc, tws, p2 * 2, wr, wi); xr[2] = y2r*wr - y2i*wi; xi[2] = y2i*wr + y2r*wi;
        tw_lookup(twc, tws, p2 * 3, wr, wi); xr[3] = y3r*wr - y3i*wi; xi[3] = y3i*wr + y3r*wi;
    }

#pragma unroll
    for (int t = 0; t < 6; ++t) {
        int m = 1 << t;
        int j = lane & (m - 1);
        int ti = j << (8 - t);
        float wc = twc[ti], wsn = tws[ti];
        bool hi = (lane & m) != 0;
#pragma unroll
        for (int d = 0; d < 4; ++d) {
            float pR = __shfl_xor(xr[d], m, 64);
            float pI = __shfl_xor(xi[d], m, 64);
            float bR = hi ? xr[d] : pR;
            float bI = hi ? xi[d] : pI;
            float aR = hi ? pR : xr[d];
            float aI = hi ? pI : xi[d];
            float wbR = wc * bR - wsn * bI;
            float wbI = wc * bI + wsn * bR;
            xr[d] = hi ? aR - wbR : aR + wbR;
            xi[d] = hi ? aI - wbI : aI + wbI;
        }
    }
}

// fftA body: k2-transform, f16 in / f16 out. bx in [0,512), 512 threads.
__device__ __forceinline__ void fftA_body(const h2* __restrict__ gridh,
                                          h2* __restrict__ Ch, int bx, int t,
                                          float* sR, float* sI,
                                          float* twc, float* tws)
{
    int lane = t & 63;
    int w = t >> 6;
    int x  = bx & 7;                              // XCD = k1 band
    int b  = (bx >> 3) & 7;
    int k1base = (x << 6) | (((bx >> 6) & 7) << 3);
    int k1 = k1base + w;

    if (t < 256) {
        float ang = (float)(2.0 * M_PI / 512.0) * (float)t;
        float s, c; sincosf(ang, &s, &c);
        twc[t] = c; tws[t] = s;
    }

    const h2* row = gridh + ((size_t)b << 18) + ((size_t)k1 << 9);
    int p = __brev((unsigned)lane) >> 26;
    float xr[8], xi[8];
#pragma unroll
    for (int a = 0; a < 8; ++a) {
        h2 v = row[p + (a << 6)];
        xr[a] = (float)v[0]; xi[a] = (float)v[1];
    }
    __syncthreads();                       // table ready

    wave_fft512(xr, xi, lane, twc, tws);

    bool act = (lane < 16) | (lane >= 48);
    int lpp = (lane < 16) ? lane : (lane - 32);   // [0,32)
    if (act) {
#pragma unroll
        for (int d = 0; d < 8; ++d) {
            int addr = w * 264 + d * 33 + lpp;    // conflict-free swizzle
            sR[addr] = xr[d];
            sI[addr] = xi[d];
        }
    }
    __syncthreads();

#pragma unroll
    for (int pp = 0; pp < 4; ++pp) {
        int idx = pp * 512 + t;                   // [0,2048) = 256 s2 x 8 k1
        int kk = idx & 7;
        int s2 = idx >> 3;
        int v = (s2 + 128) & 255;                 // v = 8*lpp + d
        int d = v & 7;
        int lp = v >> 3;
        int addr = kk * 264 + d * 33 + lp;
        h2 o;
        o[0] = (_Float16)sR[addr];
        o[1] = (_Float16)sI[addr];
        Ch[(((size_t)(b << 8) + s2) << 9) + k1base + kk] = o;
    }
}

// fftB body: split-row, f16 input. bx in [0,512), 512 threads.
__device__ __forceinline__ void fftB_body(const h2* __restrict__ Ch,
                                          float* __restrict__ imgT, float beta2,
                                          float* __restrict__ pmin,
                                          float* __restrict__ pmax,
                                          int bx, int t,
                                          float* twc, float* tws, float* invd,
                                          float (*wor)[256], float* wmn, float* wmx)
{
    int lane = t & 63;
    int w = t >> 6;                    // [0,8)
    int row = w >> 1;                  // [0,4)
    int odd = w & 1;
    int rowid = bx * 4 + row;          // [0,2048) = b*256 + s2
    int b = rowid >> 8;                // uniform across block (4 | 256)
    int s2 = rowid & 255;

    if (t < 256) {
        float ang = (float)(2.0 * M_PI / 512.0) * (float)t;
        float s, c; sincosf(ang, &s, &c);
        twc[t] = c; tws[t] = s;
    } else if (t < 512) {
        int i = t - 256;
        const float XF = (float)(M_PI * (double)JJ / (double)KK);
        float n = (float)(i - 128);
        float xf = XF * n;
        float arg = beta2 - xf * xf;
        float sq = sqrtf(arg);
        invd[i] = sq / sinhf(sq);      // 1/d(i-128)
    }

    const h2* rowp = Ch + ((size_t)rowid << 9);
    int p = __brev((unsigned)lane) >> 26;
    float xr[4], xi[4];
#pragma unroll
    for (int a = 0; a < 4; ++a) {
        h2 v = rowp[((p + (a << 6)) << 1) | odd];   // even/odd samples
        xr[a] = (float)v[0]; xi[a] = (float)v[1];
    }
    __syncthreads();                   // tables ready

    wave_fft256(xr, xi, lane, twc, tws);   // lane holds F[4*lane + d]

    if (odd) {
        float4 wo;
#pragma unroll
        for (int d = 0; d < 4; ++d) {
            int k = (lane << 2) + d;
            ((float*)&wo)[d] = xr[d] * twc[k] - xi[d] * tws[k];
        }
        *(float4*)&wor[row][lane << 2] = wo;
    }
    __syncthreads();                   // wor ready

    if (!odd) {
        const float INVK2 = 1.0f / ((float)KK * (float)KK);
        float sbase = INVK2 * invd[s2];
        float lmin = 1e30f, lmax = -1e30f;
        float4 wo = *(const float4*)&wor[row][lane << 2];
        float vals[4];
#pragma unroll
        for (int d = 0; d < 4; ++d) {
            int k = (lane << 2) + d;
            float e = xr[d];                       // re(E[k])
            float woK = ((const float*)&wo)[d];
            float xre = (k < 128) ? (e + woK) : (e - woK);
            int r = (k + 128) & 255;
            float o = xre * sbase * invd[r];
            vals[d] = o;
            lmin = fminf(lmin, o);
            lmax = fmaxf(lmax, o);
        }
        int r0run = ((lane << 2) + 128) & 255;     // 4-aligned, no wrap straddle
        *(float4*)(imgT + ((size_t)b << 16) + (s2 << 8) + r0run) =
            make_float4(vals[0], vals[1], vals[2], vals[3]);
#pragma unroll
        for (int off = 32; off >= 1; off >>= 1) {
            lmin = fminf(lmin, __shfl_xor(lmin, off, 64));
            lmax = fmaxf(lmax, __shfl_xor(lmax, off, 64));
        }
        if (lane == 0) { wmn[row] = lmin; wmx[row] = lmax; }
    }
    __syncthreads();
    if (t == 0) {
        float mn = fminf(fminf(wmn[0], wmn[1]), fminf(wmn[2], wmn[3]));
        float mx = fmaxf(fmaxf(wmx[0], wmx[1]), fmaxf(wmx[2], wmx[3]));
        pmin[bx] = mn;
        pmax[bx] = mx;
    }
}

// norm body: normalize + transpose imgT[b][s2][r] -> out[b][r][s2].
__device__ __forceinline__ void norm_body(const float* __restrict__ imgT,
                                          const float* __restrict__ pmin,
                                          const float* __restrict__ pmax,
                                          float* __restrict__ out,
                                          int bx, int t, int nthr,
                                          float (*tile)[65], float* s_mn, float* s_inv)
{
    int b = bx >> 4;
    int tl = bx & 15;
    int r0 = (tl & 3) << 6;
    int s0 = (tl >> 2) << 6;
    int tr = t & 63;
    int ts = t >> 6;
    int nts = nthr >> 6;

    if (t < 64) {                      // fftB blocks [64b, 64b+64) = batch b
        float mn = pmin[(b << 6) + t];
        float mx = pmax[(b << 6) + t];
#pragma unroll
        for (int off = 32; off >= 1; off >>= 1) {
            mn = fminf(mn, __shfl_xor(mn, off, 64));
            mx = fmaxf(mx, __shfl_xor(mx, off, 64));
        }
        if (t == 0) { *s_mn = mn; *s_inv = 1.0f / (mx - mn); }
    }

    const float* src = imgT + ((size_t)b << 16);
    for (int s2i = ts; s2i < 64; s2i += nts)
        tile[s2i][tr] = src[((s0 + s2i) << 8) + r0 + tr];
    __syncthreads();

    float mn = *s_mn, inv = *s_inv;
    float* dst = out + ((size_t)b << 16);
    for (int ri = ts; ri < 64; ri += nts)
        dst[((r0 + ri) << 8) + s0 + tr] = (tile[tr][ri] - mn) * inv;
}

// ---------- kernels ----------

__global__ __launch_bounds__(256) void count_bins(
    const float2* __restrict__ uv2, int* __restrict__ counts,
    float* __restrict__ lut, float beta, float inv_i0b)
{
    int m = blockIdx.x * 256 + threadIdx.x;
    if (m < 1024) {
        float t = -3.0f + (6.0f / 1023.0f) * (float)m;
        lut[m] = kbf(t, beta, inv_i0b);
    }
    if (m >= MPTS) return;
    float2 u = uv2[m];
    int b0 = (int)floorf(u.x * KF_SCALE) & (KK - 1);
    int b1 = (int)floorf(u.y * KF_SCALE) & (KK - 1);
    atomicAdd(&counts[(b0 << 9) | b1], 1);
}

// scan_a: block b = k1-row b. Block-local exclusive scan of counts -> offsets,
// row total -> btot[b]. (Row prefixes are rebuilt cheaply by consumers.)
__global__ __launch_bounds__(512) void scan_a(
    const int* __restrict__ counts, int* __restrict__ offsets,
    int* __restrict__ btot)
{
    __shared__ int part[8];
    int t = threadIdx.x;
    int lane = t & 63;
    int w8 = t >> 6;                   // [0,8)
    int gid = blockIdx.x * 512 + t;    // [0, NBINS)

    int v = counts[gid];
    int x = wave_scan(v, lane);
    if (lane == 63) part[w8] = x;
    __syncthreads();
    if (t < 8) {
        int pq = part[t];
#pragma unroll
        for (int off = 1; off < 8; off <<= 1) {
            int y = __shfl_up(pq, off, 64);
            if (t >= off) pq += y;
        }
        part[t] = pq;
    }
    __syncthreads();
    int incl = x + ((w8 > 0) ? part[w8 - 1] : 0);
    offsets[gid] = incl - v;           // row-local exclusive
    if (t == 511) btot[blockIdx.x] = incl;
}

__global__ __launch_bounds__(256) void fill_records(
    const float2* __restrict__ uv2,
    const float* __restrict__ y_real, const float* __restrict__ y_imag,
    const float* __restrict__ weights, const int* __restrict__ offsets,
    const int* __restrict__ btot,
    int* __restrict__ counts, char* __restrict__ recW, char* __restrict__ recY,
    const float* __restrict__ lut)
{
    __shared__ float sT[1024];
    __shared__ int sPref[513];
    int tid = threadIdx.x;
#pragma unroll
    for (int q = 0; q < 4; ++q) sT[q * 256 + tid] = lut[q * 256 + tid];
    build_row_prefix(btot, sPref, tid);
    __syncthreads();
    int m = blockIdx.x * 256 + tid;
    if (m >= MPTS) return;
    fill_point(uv2, y_real, y_imag, weights, offsets, sPref, counts,
               recW, recY, sT, m);
}

// gather: DIRECT from recW/recY (split 32B arrays -> ~2x fewer L1 line
// requests vs the 64B record), one contiguous CSR loop per row per lane.
// Wrapping lanes (c1<3 or c1>=509; <=6 per wave, only in 2/16 waves) take a
// statically-unrolled per-bin loop with exact wrap-aware ends. No LDS
// staging. Summation order/values bit-identical to rounds 3-7.
__global__ __launch_bounds__(256) void gather_grid(
    const int* __restrict__ offsets, const int* __restrict__ btot,
    const char* __restrict__ recW, const char* __restrict__ recY,
    h2* __restrict__ gridh)
{
    __shared__ int sPref[513];
    int t = threadIdx.x;
    build_row_prefix(btot, sPref, t);
    __syncthreads();

    int w = t >> 6;
    int lane = t & 63;
    int j = blockIdx.x;
    int half = lane >> 5;
    int l32 = lane & 31;
    int xcd = j & 7;
    int c0 = (xcd << 6) + ((j >> 3) & 63);
    int q4 = j >> 9;
    int c1base = (q4 << 7) + (w << 5);
    int c1 = c1base + l32;
    bool lwrap = (c1 < 3) || (c1 >= 509);   // per-lane; whole-wave execz if none
    int li = min(lane, 37);

    float aR[4], aI[4];
#pragma unroll
    for (int b = 0; b < 4; ++b) { aR[b] = 0.0f; aI[b] = 0.0f; }

    // preload all 6 rows' offset windows (independent L2 loads, all in flight)
    int vec[6], Pj[6], Ej[6];
#pragma unroll
    for (int j0 = 0; j0 < 6; ++j0) {
        int r0 = (c0 - (j0 - 2)) & (KK - 1);
        Pj[j0] = sPref[r0];
        Ej[j0] = sPref[r0 + 1];
        vec[j0] = offsets[(r0 << 9) + ((c1base - 3 + li) & 511)];
    }

#pragma unroll
    for (int j0 = 0; j0 < 6; ++j0) {
        int P = Pj[j0];
        int B[7];
#pragma unroll
        for (int d = 0; d < 7; ++d)
            B[d] = P + __shfl(vec[j0], l32 + d, 64);

        if (!lwrap) {
            // single contiguous range [B0,B6); dpr via 5 register compares
            for (int p = B[0]; p < B[6]; ++p) {
                const char* rw = recW + (size_t)p * 32;
                int dpr = (p >= B[1]) + (p >= B[2]) + (p >= B[3]) +
                          (p >= B[4]) + (p >= B[5]);
                float w0 = (float)*(const _Float16*)(rw + j0 * 2);
                float w1 = (float)*(const _Float16*)(rw + 22 - dpr * 2);
                float ww = w0 * w1;
                h8 yv = *(const h8*)(recY + (size_t)p * 32 + (half << 4));
#pragma unroll
                for (int b = 0; b < 4; ++b) {
                    aR[b] += (float)yv[2 * b]     * ww;   // v_fma_mix
                    aI[b] += (float)yv[2 * b + 1] * ww;
                }
            }
        } else {
            // wrap-aware per-bin loops (static d); bin d = [B[d], end_d)
            int rowEnd = Ej[j0];
            int cm3 = c1 - 3;
#pragma unroll
            for (int d = 0; d < 6; ++d) {
                int col = (cm3 + d) & 511;
                int ed = (col == 511) ? rowEnd : B[d + 1];
                for (int p = B[d]; p < ed; ++p) {
                    const char* rw = recW + (size_t)p * 32;
                    float w0 = (float)*(const _Float16*)(rw + j0 * 2);
                    float w1 = (float)*(const _Float16*)(rw + 22 - d * 2);
                    float ww = w0 * w1;
                    h8 yv = *(const h8*)(recY + (size_t)p * 32 + (half << 4));
#pragma unroll
                    for (int b = 0; b < 4; ++b) {
                        aR[b] += (float)yv[2 * b]     * ww;
                        aI[b] += (float)yv[2 * b + 1] * ww;
                    }
                }
            }
        }
    }

    int c = (c0 << 9) + c1;
#pragma unroll
    for (int b = 0; b < 4; ++b) {
        h2 v;
        v[0] = (_Float16)aR[b];
        v[1] = (_Float16)aI[b];
        gridh[((size_t)((half << 2) + b) << 18) + c] = v;
    }
}

__global__ __launch_bounds__(512) void fftA(
    const h2* __restrict__ gridh, h2* __restrict__ Ch)
{
    __shared__ float sR[2112], sI[2112];
    __shared__ float twc[256], tws[256];
    fftA_body(gridh, Ch, blockIdx.x, threadIdx.x, sR, sI, twc, tws);
}

__global__ __launch_bounds__(512) void fftB(
    const h2* __restrict__ Ch, float* __restrict__ imgT, float beta2,
    float* __restrict__ pmin, float* __restrict__ pmax)
{
    __shared__ float twc[256], tws[256];
    __shared__ float invd[256];
    __shared__ __align__(16) float wor[4][256];
    __shared__ float wmn[4], wmx[4];
    fftB_body(Ch, imgT, beta2, pmin, pmax, blockIdx.x, threadIdx.x,
              twc, tws, invd, wor, wmn, wmx);
}

__global__ __launch_bounds__(256) void norm_t(
    const float* __restrict__ imgT, const float* __restrict__ pmin,
    const float* __restrict__ pmax, float* __restrict__ out)
{
    __shared__ float tile[64][65];
    __shared__ float s_mn, s_inv;
    norm_body(imgT, pmin, pmax, out, blockIdx.x, threadIdx.x, 256,
              tile, &s_mn, &s_inv);
}

// ---------- host ----------

static double i0_host(double x) {
    double sum = 1.0, term = 1.0;
    double q = x * x * 0.25;
    for (int k = 1; k < 80; ++k) {
        term *= q / ((double)k * (double)k);
        sum += term;
        if (term < sum * 1e-17) break;
    }
    return sum;
}

extern "C" void kernel_launch(void* const* d_in, const int* in_sizes, int n_in,
                              void* d_out, int out_size, void* d_ws, size_t ws_size,
                              hipStream_t stream)
{
    const float* y_real  = (const float*)d_in[0];
    const float* y_imag  = (const float*)d_in[1];
    const float* weights = (const float*)d_in[2];
    const float2* uv2    = (const float2*)d_in[3];
    float* out = (float*)d_out;

    char* W = (char*)d_ws;
    // Aliased live ranges (peak ~24.4 MB):
    //  W[0,16M): counts[1M] (binning) -> gridh [0,8M) f16 (gather->fftA)
    //            -> imgT [0,2M) (fftB->norm)
    //  A=W+16M:  recW [0,3.2M) + recY [3.2M,6.4M) + offsets [6.4M,7.45M)
    //            (bin->gather) -> Ch [0,4M) f16 (fftA->fftB);
    //            pmin/pmax at [8.4M); lut at [8.404M); btot at [8.408M)
    //            (btot OUTSIDE gridh range: gather reads btot while writing gridh)
    h2*       gridh   = (h2*)W;                            // 8 MB (f16 pairs)
    int*      counts  = (int*)W;                           // 1 MB (aliases gridh)
    float*    imgT    = (float*)W;                         // 2 MB (aliases gridh)
    char*     A       = W + (size_t)16 * 1024 * 1024;
    char*     recW    = A;                                 // 3,200,000 B
    char*     recY    = A + 3200000;                       // 3,200,000 B
    int*      offsets = (int*)(A + 6400000);               // 1,048,576 B
    h2*       Ch      = (h2*)A;                            // 4 MB (aliases recW/recY)
    float*    pmin    = (float*)(A + 8400000);             // 2 KB
    float*    pmax    = (float*)(A + 8402048);             // 2 KB
    float*    lut     = (float*)(A + 8404096);             // 4 KB
    int*      btot    = (int*)(A + 8408192);               // 2 KB

    double beta_d = M_PI * sqrt(19.45);   // BETA with alpha=2
    float beta = (float)beta_d;
    float inv_i0b = (float)(1.0 / i0_host(beta_d));
    float beta2 = (float)(beta_d * beta_d);

    hipMemsetAsync(counts, 0, NBINS * sizeof(int), stream);

    count_bins<<<(MPTS + 255) / 256, 256, 0, stream>>>(
        uv2, counts, lut, beta, inv_i0b);

    scan_a<<<512, 512, 0, stream>>>(counts, offsets, btot);

    fill_records<<<(MPTS + 255) / 256, 256, 0, stream>>>(
        uv2, y_real, y_imag, weights, offsets, btot, counts, recW, recY, lut);

    gather_grid<<<2048, 256, 0, stream>>>(offsets, btot, recW, recY, gridh);

    fftA<<<512, 512, 0, stream>>>(gridh, Ch);

    fftB<<<512, 512, 0, stream>>>(Ch, imgT, beta2, pmin, pmax);

    norm_t<<<128, 256, 0, stream>>>(imgT, pmin, pmax, out);
}

// Round 10
// 136.628 us; speedup vs baseline: 1.0211x; 1.0211x over previous
//
#include <hip/hip_runtime.h>
#include <math.h>

// Problem constants
#define NN 256
#define KK 512
#define JJ 6
#define BB 8
#define MPTS 100000
#define NBINS (KK * KK)
// K/(2*pi)
#define KF_SCALE 81.48733086305615f

typedef _Float16 h8 __attribute__((ext_vector_type(8)));
typedef _Float16 h2 __attribute__((ext_vector_type(2)));

// ---------- device helpers ----------

// Abramowitz & Stegun 9.8.1 / 9.8.2 modified Bessel I0, float
__device__ __forceinline__ float i0f_dev(float x) {
    float ax = fabsf(x);
    if (ax < 3.75f) {
        float t = x / 3.75f; t *= t;
        return 1.0f + t*(3.5156229f + t*(3.0899424f + t*(1.2067492f +
               t*(0.2659732f + t*(0.0360768f + t*0.0045813f)))));
    } else {
        float t = 3.75f / ax;
        return (expf(ax) * rsqrtf(ax)) *
               (0.39894228f + t*(0.01328592f + t*(0.00225319f + t*(-0.00157565f +
                t*(0.00916281f + t*(-0.02057706f + t*(0.02635537f +
                t*(-0.01647633f + t*0.00392377f))))))));
    }
}

__device__ __forceinline__ float kbf(float t, float beta, float inv_i0b) {
    float u = t * (1.0f / 3.0f);       // 2*t/J, J=6
    float q = fmaxf(1.0f - u * u, 0.0f);
    return i0f_dev(beta * sqrtf(q)) * inv_i0b;
}

// inclusive wave scan (64 lanes)
__device__ __forceinline__ int wave_scan(int x, int lane) {
#pragma unroll
    for (int off = 1; off < 64; off <<= 1) {
        int y = __shfl_up(x, off, 64);
        if (lane >= off) x += y;
    }
    return x;
}

// Build sPref[0..512] = exclusive row-prefix of btot[512] (sPref[512]=MPTS).
// Runs on wave 0 of the block (threads 0..63); caller must __syncthreads after.
__device__ __forceinline__ void build_row_prefix(const int* __restrict__ btot,
                                                 int* sPref, int t)
{
    if (t < 64) {
        int carry = 0;
        if (t == 0) sPref[0] = 0;
#pragma unroll
        for (int k = 0; k < 8; ++k) {
            int x = btot[k * 64 + t];
            int incl = wave_scan(x, t);
            sPref[k * 64 + t + 1] = incl + carry;
            carry += __shfl(incl, 63, 64);
        }
    }
}

// KB weight via 1024-entry LUT over t in [-3,3], linear interp (err ~4e-4)
__device__ __forceinline__ float kb_lut(const float* __restrict__ sT, float t) {
    float u = (t + 3.0f) * (1023.0f / 6.0f);
    int i = (int)u;
    i = min(i, 1022);
    float f = u - (float)i;
    float a = sT[i];
    return a + f * (sT[i + 1] - sT[i]);
}

// twiddle from 256-entry half-circle table: e^{+i*2*pi*idx/512}, idx in [0,512)
__device__ __forceinline__ void tw_lookup(const float* __restrict__ twc,
                                          const float* __restrict__ tws,
                                          int idx, float& wr, float& wi) {
    float sg = (idx & 256) ? -1.0f : 1.0f;
    int ib = idx & 255;
    wr = sg * twc[ib];
    wi = sg * tws[ib];
}

// ---------- stage bodies ----------

// fill one point's 64B record into its CSR slot.
// offsets = block-local (per-row) exclusive scan; sPref = row prefixes (LDS).
// 64B record == one cache line: w0/w1/yv co-resident (key for gather).
__device__ __forceinline__ void fill_point(
    const float2* __restrict__ uv2,
    const float* __restrict__ y_real, const float* __restrict__ y_imag,
    const float* __restrict__ weights, const int* __restrict__ offsets,
    const int* sPref,
    int* counts, char* rec, const float* sT, int m)
{
    float2 u = uv2[m];
    float kf0 = u.x * KF_SCALE;
    float kf1 = u.y * KF_SCALE;
    float f0 = floorf(kf0), f1 = floorf(kf1);
    float fr0 = kf0 - f0, fr1 = kf1 - f1;
    int b0r = (int)f0 & (KK - 1);
    int b1c = (int)f1 & (KK - 1);
    int bin = (b0r << 9) | b1c;
    int old = atomicSub(&counts[bin], 1);
    int slot = sPref[b0r] + offsets[bin] + old - 1;

    _Float16 hw[12];
#pragma unroll
    for (int j = 0; j < JJ; ++j) {
        hw[j]     = (_Float16)kb_lut(sT, (float)(j - 2) - fr0);
        hw[6 + j] = (_Float16)kb_lut(sT, (float)(j - 2) - fr1);
    }

    float4 c0v, c1v;
    _Float16* p0 = (_Float16*)&c0v;
    _Float16* p1 = (_Float16*)&c1v;
#pragma unroll
    for (int j = 0; j < 8; ++j) p0[j] = hw[j];        // w0[0..5], w1[0..1]
#pragma unroll
    for (int j = 0; j < 4; ++j) p1[j] = hw[8 + j];    // w1[2..5]
    ((int*)&c1v)[2] = b1c;
    ((int*)&c1v)[3] = 0;

    float wm = weights[m];
    h8 ha, hb;
#pragma unroll
    for (int b = 0; b < 4; ++b) {
        ha[2 * b]     = (_Float16)(y_real[b * MPTS + m] * wm);
        ha[2 * b + 1] = (_Float16)(y_imag[b * MPTS + m] * wm);
        hb[2 * b]     = (_Float16)(y_real[(b + 4) * MPTS + m] * wm);
        hb[2 * b + 1] = (_Float16)(y_imag[(b + 4) * MPTS + m] * wm);
    }

    float4* dst = (float4*)(rec + (size_t)slot * 64);
    dst[0] = c0v;
    dst[1] = c1v;
    dst[2] = *(float4*)&ha;
    dst[3] = *(float4*)&hb;
}

// ---- gather inner accum, wrap path (bin1-based; verbatim round-3 logic) ----
__device__ __forceinline__ void gather_accum(
    const char* myl, int pLo, int pHi, int pc, int c1, int j0, int half,
    float aR[4], float aI[4])
{
    for (int p = pLo; p < pHi; ++p) {
        const char* rp = myl + (p - pc) * 88;
        int bin1 = *(const int*)(rp + 24);
        int idx = (c1 - bin1 + 2) & 511;   // wrap-exact o1+2
        bool ok = idx <= 5;
        idx = ok ? idx : 0;
        float w0 = (float)*(const _Float16*)(rp + j0 * 2);
        float w1 = (float)*(const _Float16*)(rp + 12 + idx * 2);
        float ww = ok ? w0 * w1 : 0.0f;
        h8 yv = *(const h8*)(rp + 32 + (half << 4));
#pragma unroll
        for (int b = 0; b < 4; ++b) {
            aR[b] += (float)yv[2 * b]     * ww;   // v_fma_mix
            aI[b] += (float)yv[2 * b + 1] * ww;
        }
    }
}

// wrap-path gather (verbatim round-3 logic; taken by 2/16 of waves).
__device__ void gather_strip_wrap(
    const int* __restrict__ offsets, const int* sPref,
    const char* __restrict__ rec,
    h2* __restrict__ gridh, char* myl, int j, int w, int lane)
{
    int half = lane >> 5;
    int l32 = lane & 31;
    int xcd = j & 7;
    int c0 = (xcd << 6) + ((j >> 3) & 63);
    int q4 = j >> 9;
    int c1base = (q4 << 7) + (w << 5);
    int c1 = c1base + l32;
    int wa = c1 - 3, wb = c1 + 2;

    float aR[4], aI[4];
#pragma unroll
    for (int b = 0; b < 4; ++b) { aR[b] = 0.0f; aI[b] = 0.0f; }

    for (int j0 = 0; j0 < JJ; ++j0) {
        int r0 = (c0 - (j0 - 2)) & (KK - 1);
        int rowbase = r0 << 9;
        int P = sPref[r0];
        int rowEnd = sPref[r0 + 1];
        int lo = c1base - 3, hi = c1base + 33;
        int nseg, ga0, gb0, ga1, gb1;
        if (lo < 0)        { ga0 = lo; gb0 = -1;  ga1 = 0;   gb1 = hi; nseg = 2; }
        else if (hi > 511) { ga0 = lo; gb0 = 511; ga1 = 512; gb1 = hi; nseg = 2; }
        else               { ga0 = lo; gb0 = hi;  ga1 = 0;   gb1 = 0;  nseg = 1; }

        for (int sgi = 0; sgi < nseg; ++sgi) {
            int ga = sgi ? ga1 : ga0;
            int gb = sgi ? gb1 : gb0;
            int pstart = P + offsets[rowbase + (ga & 511)];
            int ce = (gb & 511) + 1;
            int pend = (ce == 512) ? rowEnd : P + offsets[rowbase + ce];
            int ia = max(wa, ga), ib = min(wb, gb);
            bool has = ia <= ib;
            int pA = has ? P + offsets[rowbase + (ia & 511)] : 0;
            int pB = has ? ((ib == gb) ? pend
                                       : P + offsets[rowbase + ((ib + 1) & 511)]) : 0;

            for (int pc = pstart; pc < pend; pc += 32) {
                int cnt = min(32, pend - pc);
                int sub = lane & 3;
                int prow = lane >> 2;
#pragma unroll
                for (int qq = 0; qq < 2; ++qq) {
                    if (16 * qq < cnt) {
                        int pp = min(pc + prow + 16 * qq, MPTS - 1);
                        float4 v = *(const float4*)(rec + (size_t)pp * 64 + sub * 16);
                        *(float4*)(myl + (prow + 16 * qq) * 88 + sub * 16) = v;
                    }
                }
                gather_accum(myl, max(pA, pc), min(pB, pc + cnt), pc,
                             c1, j0, half, aR, aI);
            }
        }
    }

    int c = (c0 << 9) + c1;
#pragma unroll
    for (int b = 0; b < 4; ++b) {
        h2 v;
        v[0] = (_Float16)aR[b];
        v[1] = (_Float16)aI[b];
        gridh[((size_t)((half << 2) + b) << 18) + c] = v;
    }
}

// ---------- per-wave 512-pt FFT: 8(reg) x 64(lanes via shfl), sign +i ----------
// All twiddles from the 256-entry LDS table (half circle + sign flip).
__device__ __forceinline__ void wave_fft512(float xr[8], float xi[8], int lane,
                                            const float* __restrict__ twc,
                                            const float* __restrict__ tws)
{
    float a0r = xr[0]+xr[4], a0i = xi[0]+xi[4];
    float a4r = xr[0]-xr[4], a4i = xi[0]-xi[4];
    float a2r = xr[2]+xr[6], a2i = xi[2]+xi[6];
    float a6r = xr[2]-xr[6], a6i = xi[2]-xi[6];
    float a1r = xr[1]+xr[5], a1i = xi[1]+xi[5];
    float a5r = xr[1]-xr[5], a5i = xi[1]-xi[5];
    float a3r = xr[3]+xr[7], a3i = xi[3]+xi[7];
    float a7r = xr[3]-xr[7], a7i = xi[3]-xi[7];
    float b0r = a0r+a2r, b0i = a0i+a2i;
    float b2r = a0r-a2r, b2i = a0i-a2i;
    float b4r = a4r-a6i, b4i = a4i+a6r;    // a4 + i*a6
    float b6r = a4r+a6i, b6i = a4i-a6r;    // a4 - i*a6
    float b1r = a1r+a3r, b1i = a1i+a3i;
    float b3r = a1r-a3r, b3i = a1i-a3i;
    float b5r = a5r-a7i, b5i = a5i+a7r;
    float b7r = a5r+a7i, b7i = a5i-a7r;
    const float S2 = 0.70710678118654752f;
    float w5r = S2*(b5r-b5i), w5i = S2*(b5r+b5i);     // W8^1 * b5
    float w7r = -S2*(b7r+b7i), w7i = S2*(b7r-b7i);    // W8^3 * b7
    float y1r = b4r+w5r, y1i = b4i+w5i;
    float y5r = b4r-w5r, y5i = b4i-w5i;
    float y2r = b2r-b3i, y2i = b2i+b3r;    // b2 + i*b3
    float y6r = b2r+b3i, y6i = b2i-b3r;
    float y3r = b6r+w7r, y3i = b6i+w7i;
    float y7r = b6r-w7r, y7i = b6i-w7i;

    int p = __brev((unsigned)lane) >> 26;
    xr[0] = b0r+b1r; xi[0] = b0i+b1i;
    {
        float wr, wi;
        tw_lookup(twc, tws, p,     wr, wi); xr[1] = y1r*wr - y1i*wi; xi[1] = y1i*wr + y1r*wi;
        tw_lookup(twc, tws, p * 2, wr, wi); xr[2] = y2r*wr - y2i*wi; xi[2] = y2i*wr + y2r*wi;
        tw_lookup(twc, tws, p * 3, wr, wi); xr[3] = y3r*wr - y3i*wi; xi[3] = y3i*wr + y3r*wi;
        float y4r = b0r-b1r, y4i = b0i-b1i;
        tw_lookup(twc, tws, p * 4, wr, wi); xr[4] = y4r*wr - y4i*wi; xi[4] = y4i*wr + y4r*wi;
        tw_lookup(twc, tws, p * 5, wr, wi); xr[5] = y5r*wr - y5i*wi; xi[5] = y5i*wr + y5r*wi;
        tw_lookup(twc, tws, p * 6, wr, wi); xr[6] = y6r*wr - y6i*wi; xi[6] = y6i*wr + y6r*wi;
        tw_lookup(twc, tws, p * 7, wr, wi); xr[7] = y7r*wr - y7i*wi; xi[7] = y7i*wr + y7r*wi;
    }

#pragma unroll
    for (int t = 0; t < 6; ++t) {
        int m = 1 << t;
        int j = lane & (m - 1);
        int ti = j << (8 - t);                 // pi*j/m in 512-root table units
        float wc = twc[ti], wsn = tws[ti];
        bool hi = (lane & m) != 0;
#pragma unroll
        for (int d = 0; d < 8; ++d) {
            float pR = __shfl_xor(xr[d], m, 64);
            float pI = __shfl_xor(xi[d], m, 64);
            float bR = hi ? xr[d] : pR;
            float bI = hi ? xi[d] : pI;
            float aR = hi ? pR : xr[d];
            float aI = hi ? pI : xi[d];
            float wbR = wc * bR - wsn * bI;
            float wbI = wc * bI + wsn * bR;
            xr[d] = hi ? aR - wbR : aR + wbR;
            xi[d] = hi ? aI - wbI : aI + wbI;
        }
    }
}

// ---------- per-wave 256-pt FFT: 4(reg) x 64(lanes), sign +i ----------
__device__ __forceinline__ void wave_fft256(float xr[4], float xi[4], int lane,
                                            const float* __restrict__ twc,
                                            const float* __restrict__ tws)
{
    float t0r = xr[0]+xr[2], t0i = xi[0]+xi[2];
    float t1r = xr[0]-xr[2], t1i = xi[0]-xi[2];
    float t2r = xr[1]+xr[3], t2i = xi[1]+xi[3];
    float t3r = xr[1]-xr[3], t3i = xi[1]-xi[3];
    float y1r = t1r-t3i, y1i = t1i+t3r;    // t1 + i*t3
    float y3r = t1r+t3i, y3i = t1i-t3r;    // t1 - i*t3

    int p2 = (__brev((unsigned)lane) >> 26) << 1;   // 2*p, table units
    xr[0] = t0r+t2r; xi[0] = t0i+t2i;
    {
        float wr, wi;
        tw_lookup(twc, tws, p2,     wr, wi); xr[1] = y1r*wr - y1i*wi; xi[1] = y1i*wr + y1r*wi;
        float y2r = t0r-t2r, y2i = t0i-t2i;
        tw_lookup(twc, tws, p2 * 2, wr, wi); xr[2] = y2r*wr - y2i*wi; xi[2] = y2i*wr + y2r*wi;
        tw_lookup(twc, tws, p2 * 3, wr, wi); xr[3] = y3r*wr - y3i*wi; xi[3] = y3i*wr + y3r*wi;
    }

#pragma unroll
    for (int t = 0; t < 6; ++t) {
        int m = 1 << t;
        int j = lane & (m - 1);
        int ti = j << (8 - t);
        float wc = twc[ti], wsn = tws[ti];
        bool hi = (lane & m) != 0;
#pragma unroll
        for (int d = 0; d < 4; ++d) {
            float pR = __shfl_xor(xr[d], m, 64);
            float pI = __shfl_xor(xi[d], m, 64);
            float bR = hi ? xr[d] : pR;
            float bI = hi ? xi[d] : pI;
            float aR = hi ? pR : xr[d];
            float aI = hi ? pI : xi[d];
            float wbR = wc * bR - wsn * bI;
            float wbI = wc * bI + wsn * bR;
            xr[d] = hi ? aR - wbR : aR + wbR;
            xi[d] = hi ? aI - wbI : aI + wbI;
        }
    }
}

// fftA body: k2-transform, f16 in / f16 out. bx in [0,512), 512 threads.
__device__ __forceinline__ void fftA_body(const h2* __restrict__ gridh,
                                          h2* __restrict__ Ch, int bx, int t,
                                          float* sR, float* sI,
                                          float* twc, float* tws)
{
    int lane = t & 63;
    int w = t >> 6;
    int x  = bx & 7;                              // XCD = k1 band
    int b  = (bx >> 3) & 7;
    int k1base = (x << 6) | (((bx >> 6) & 7) << 3);
    int k1 = k1base + w;

    if (t < 256) {
        float ang = (float)(2.0 * M_PI / 512.0) * (float)t;
        float s, c; sincosf(ang, &s, &c);
        twc[t] = c; tws[t] = s;
    }

    const h2* row = gridh + ((size_t)b << 18) + ((size_t)k1 << 9);
    int p = __brev((unsigned)lane) >> 26;
    float xr[8], xi[8];
#pragma unroll
    for (int a = 0; a < 8; ++a) {
        h2 v = row[p + (a << 6)];
        xr[a] = (float)v[0]; xi[a] = (float)v[1];
    }
    __syncthreads();                       // table ready

    wave_fft512(xr, xi, lane, twc, tws);

    bool act = (lane < 16) | (lane >= 48);
    int lpp = (lane < 16) ? lane : (lane - 32);   // [0,32)
    if (act) {
#pragma unroll
        for (int d = 0; d < 8; ++d) {
            int addr = w * 264 + d * 33 + lpp;    // conflict-free swizzle
            sR[addr] = xr[d];
            sI[addr] = xi[d];
        }
    }
    __syncthreads();

#pragma unroll
    for (int pp = 0; pp < 4; ++pp) {
        int idx = pp * 512 + t;                   // [0,2048) = 256 s2 x 8 k1
        int kk = idx & 7;
        int s2 = idx >> 3;
        int v = (s2 + 128) & 255;                 // v = 8*lpp + d
        int d = v & 7;
        int lp = v >> 3;
        int addr = kk * 264 + d * 33 + lp;
        h2 o;
        o[0] = (_Float16)sR[addr];
        o[1] = (_Float16)sI[addr];
        Ch[(((size_t)(b << 8) + s2) << 9) + k1base + kk] = o;
    }
}

// fftB body: split-row, f16 input. bx in [0,512), 512 threads.
__device__ __forceinline__ void fftB_body(const h2* __restrict__ Ch,
                                          float* __restrict__ imgT, float beta2,
                                          float* __restrict__ pmin,
                                          float* __restrict__ pmax,
                                          int bx, int t,
                                          float* twc, float* tws, float* invd,
                                          float (*wor)[256], float* wmn, float* wmx)
{
    int lane = t & 63;
    int w = t >> 6;                    // [0,8)
    int row = w >> 1;                  // [0,4)
    int odd = w & 1;
    int rowid = bx * 4 + row;          // [0,2048) = b*256 + s2
    int b = rowid >> 8;                // uniform across block (4 | 256)
    int s2 = rowid & 255;

    if (t < 256) {
        float ang = (float)(2.0 * M_PI / 512.0) * (float)t;
        float s, c; sincosf(ang, &s, &c);
        twc[t] = c; tws[t] = s;
    } else if (t < 512) {
        int i = t - 256;
        const float XF = (float)(M_PI * (double)JJ / (double)KK);
        float n = (float)(i - 128);
        float xf = XF * n;
        float arg = beta2 - xf * xf;
        float sq = sqrtf(arg);
        invd[i] = sq / sinhf(sq);      // 1/d(i-128)
    }

    const h2* rowp = Ch + ((size_t)rowid << 9);
    int p = __brev((unsigned)lane) >> 26;
    float xr[4], xi[4];
#pragma unroll
    for (int a = 0; a < 4; ++a) {
        h2 v = rowp[((p + (a << 6)) << 1) | odd];   // even/odd samples
        xr[a] = (float)v[0]; xi[a] = (float)v[1];
    }
    __syncthreads();                   // tables ready

    wave_fft256(xr, xi, lane, twc, tws);   // lane holds F[4*lane + d]

    if (odd) {
        float4 wo;
#pragma unroll
        for (int d = 0; d < 4; ++d) {
            int k = (lane << 2) + d;
            ((float*)&wo)[d] = xr[d] * twc[k] - xi[d] * tws[k];
        }
        *(float4*)&wor[row][lane << 2] = wo;
    }
    __syncthreads();                   // wor ready

    if (!odd) {
        const float INVK2 = 1.0f / ((float)KK * (float)KK);
        float sbase = INVK2 * invd[s2];
        float lmin = 1e30f, lmax = -1e30f;
        float4 wo = *(const float4*)&wor[row][lane << 2];
        float vals[4];
#pragma unroll
        for (int d = 0; d < 4; ++d) {
            int k = (lane << 2) + d;
            float e = xr[d];                       // re(E[k])
            float woK = ((const float*)&wo)[d];
            float xre = (k < 128) ? (e + woK) : (e - woK);
            int r = (k + 128) & 255;
            float o = xre * sbase * invd[r];
            vals[d] = o;
            lmin = fminf(lmin, o);
            lmax = fmaxf(lmax, o);
        }
        int r0run = ((lane << 2) + 128) & 255;     // 4-aligned, no wrap straddle
        *(float4*)(imgT + ((size_t)b << 16) + (s2 << 8) + r0run) =
            make_float4(vals[0], vals[1], vals[2], vals[3]);
#pragma unroll
        for (int off = 32; off >= 1; off >>= 1) {
            lmin = fminf(lmin, __shfl_xor(lmin, off, 64));
            lmax = fmaxf(lmax, __shfl_xor(lmax, off, 64));
        }
        if (lane == 0) { wmn[row] = lmin; wmx[row] = lmax; }
    }
    __syncthreads();
    if (t == 0) {
        float mn = fminf(fminf(wmn[0], wmn[1]), fminf(wmn[2], wmn[3]));
        float mx = fmaxf(fmaxf(wmx[0], wmx[1]), fmaxf(wmx[2], wmx[3]));
        pmin[bx] = mn;
        pmax[bx] = mx;
    }
}

// norm body: normalize + transpose imgT[b][s2][r] -> out[b][r][s2].
__device__ __forceinline__ void norm_body(const float* __restrict__ imgT,
                                          const float* __restrict__ pmin,
                                          const float* __restrict__ pmax,
                                          float* __restrict__ out,
                                          int bx, int t, int nthr,
                                          float (*tile)[65], float* s_mn, float* s_inv)
{
    int b = bx >> 4;
    int tl = bx & 15;
    int r0 = (tl & 3) << 6;
    int s0 = (tl >> 2) << 6;
    int tr = t & 63;
    int ts = t >> 6;
    int nts = nthr >> 6;

    if (t < 64) {                      // fftB blocks [64b, 64b+64) = batch b
        float mn = pmin[(b << 6) + t];
        float mx = pmax[(b << 6) + t];
#pragma unroll
        for (int off = 32; off >= 1; off >>= 1) {
            mn = fminf(mn, __shfl_xor(mn, off, 64));
            mx = fmaxf(mx, __shfl_xor(mx, off, 64));
        }
        if (t == 0) { *s_mn = mn; *s_inv = 1.0f / (mx - mn); }
    }

    const float* src = imgT + ((size_t)b << 16);
    for (int s2i = ts; s2i < 64; s2i += nts)
        tile[s2i][tr] = src[((s0 + s2i) << 8) + r0 + tr];
    __syncthreads();

    float mn = *s_mn, inv = *s_inv;
    float* dst = out + ((size_t)b << 16);
    for (int ri = ts; ri < 64; ri += nts)
        dst[((r0 + ri) << 8) + s0 + tr] = (tile[tr][ri] - mn) * inv;
}

// ---------- kernels ----------

__global__ __launch_bounds__(256) void count_bins(
    const float2* __restrict__ uv2, int* __restrict__ counts,
    float* __restrict__ lut, float beta, float inv_i0b)
{
    int m = blockIdx.x * 256 + threadIdx.x;
    if (m < 1024) {
        float t = -3.0f + (6.0f / 1023.0f) * (float)m;
        lut[m] = kbf(t, beta, inv_i0b);
    }
    if (m >= MPTS) return;
    float2 u = uv2[m];
    int b0 = (int)floorf(u.x * KF_SCALE) & (KK - 1);
    int b1 = (int)floorf(u.y * KF_SCALE) & (KK - 1);
    atomicAdd(&counts[(b0 << 9) | b1], 1);
}

// scan_a: block b = k1-row b. Block-local exclusive scan of counts -> offsets,
// row total -> btot[b]. (Row prefixes are rebuilt cheaply by consumers.)
__global__ __launch_bounds__(512) void scan_a(
    const int* __restrict__ counts, int* __restrict__ offsets,
    int* __restrict__ btot)
{
    __shared__ int part[8];
    int t = threadIdx.x;
    int lane = t & 63;
    int w8 = t >> 6;                   // [0,8)
    int gid = blockIdx.x * 512 + t;    // [0, NBINS)

    int v = counts[gid];
    int x = wave_scan(v, lane);
    if (lane == 63) part[w8] = x;
    __syncthreads();
    if (t < 8) {
        int pq = part[t];
#pragma unroll
        for (int off = 1; off < 8; off <<= 1) {
            int y = __shfl_up(pq, off, 64);
            if (t >= off) pq += y;
        }
        part[t] = pq;
    }
    __syncthreads();
    int incl = x + ((w8 > 0) ? part[w8 - 1] : 0);
    offsets[gid] = incl - v;           // row-local exclusive
    if (t == 511) btot[blockIdx.x] = incl;
}

__global__ __launch_bounds__(256) void fill_records(
    const float2* __restrict__ uv2,
    const float* __restrict__ y_real, const float* __restrict__ y_imag,
    const float* __restrict__ weights, const int* __restrict__ offsets,
    const int* __restrict__ btot,
    int* __restrict__ counts, char* __restrict__ rec,
    const float* __restrict__ lut)
{
    __shared__ float sT[1024];
    __shared__ int sPref[513];
    int tid = threadIdx.x;
#pragma unroll
    for (int q = 0; q < 4; ++q) sT[q * 256 + tid] = lut[q * 256 + tid];
    build_row_prefix(btot, sPref, tid);
    __syncthreads();
    int m = blockIdx.x * 256 + tid;
    if (m >= MPTS) return;
    fill_point(uv2, y_real, y_imag, weights, offsets, sPref, counts, rec, sT, m);
}

// gather: DIRECT from rec, ONE contiguous CSR loop per row per lane.
// A lane's 6-bin window within row r0 is contiguous in CSR -> [pA,pB).
// Per point: 3 loads (all within the point's single 64B line) + dpr via 5
// boundary compares + 8 FMAs. No LDS staging, no masked accum, no bank
// conflicts. Ascending-p order per row = bit-identical summation vs rounds
// 3/5/6. Wrap waves (2/16) keep the proven staged path.
__global__ __launch_bounds__(256) void gather_grid(
    const int* __restrict__ offsets, const int* __restrict__ btot,
    const char* __restrict__ rec, h2* __restrict__ gridh)
{
    __shared__ __align__(16) char lds[4][2816];   // wrap path only
    __shared__ int sPref[513];
    int t = threadIdx.x;
    build_row_prefix(btot, sPref, t);
    __syncthreads();

    int w = t >> 6;
    int lane = t & 63;
    int j = blockIdx.x;
    int half = lane >> 5;
    int l32 = lane & 31;
    int xcd = j & 7;
    int c0 = (xcd << 6) + ((j >> 3) & 63);
    int q4 = j >> 9;
    int c1base = (q4 << 7) + (w << 5);
    int c1 = c1base + l32;

    if (c1base == 0 || c1base + 33 > 511) {       // wave-uniform branch
        gather_strip_wrap(offsets, sPref, rec, gridh, lds[w], j, w, lane);
        return;
    }

    // ---- direct single-segment path (lo >= 0, hi <= 511) ----
    int lo = c1base - 3;
    int li = min(lane, 37);

    float aR[4], aI[4];
#pragma unroll
    for (int b = 0; b < 4; ++b) { aR[b] = 0.0f; aI[b] = 0.0f; }

    // preload all 6 rows' offset windows (independent L2 loads, all in flight)
    int vec[6], Pj[6];
#pragma unroll
    for (int j0 = 0; j0 < 6; ++j0) {
        int r0 = (c0 - (j0 - 2)) & (KK - 1);
        Pj[j0] = sPref[r0];
        vec[j0] = offsets[(r0 << 9) + lo + li];
    }

#pragma unroll
    for (int j0 = 0; j0 < 6; ++j0) {
        int P = Pj[j0];
        int pA = P + __shfl(vec[j0], l32, 64);
        int B1 = P + __shfl(vec[j0], l32 + 1, 64);
        int B2 = P + __shfl(vec[j0], l32 + 2, 64);
        int B3 = P + __shfl(vec[j0], l32 + 3, 64);
        int B4 = P + __shfl(vec[j0], l32 + 4, 64);
        int B5 = P + __shfl(vec[j0], l32 + 5, 64);
        int pB = P + __shfl(vec[j0], l32 + 6, 64);

        for (int p = pA; p < pB; ++p) {
            const char* rp = rec + (size_t)p * 64;
            int dpr = (p >= B1) + (p >= B2) + (p >= B3) + (p >= B4) + (p >= B5);
            float w0 = (float)*(const _Float16*)(rp + j0 * 2);
            float w1 = (float)*(const _Float16*)(rp + 22 - dpr * 2);
            float ww = w0 * w1;
            h8 yv = *(const h8*)(rp + 32 + (half << 4));
#pragma unroll
            for (int b = 0; b < 4; ++b) {
                aR[b] += (float)yv[2 * b]     * ww;   // v_fma_mix
                aI[b] += (float)yv[2 * b + 1] * ww;
            }
        }
    }

    int c = (c0 << 9) + c1;
#pragma unroll
    for (int b = 0; b < 4; ++b) {
        h2 v;
        v[0] = (_Float16)aR[b];
        v[1] = (_Float16)aI[b];
        gridh[((size_t)((half << 2) + b) << 18) + c] = v;
    }
}

__global__ __launch_bounds__(512) void fftA(
    const h2* __restrict__ gridh, h2* __restrict__ Ch)
{
    __shared__ float sR[2112], sI[2112];
    __shared__ float twc[256], tws[256];
    fftA_body(gridh, Ch, blockIdx.x, threadIdx.x, sR, sI, twc, tws);
}

__global__ __launch_bounds__(512) void fftB(
    const h2* __restrict__ Ch, float* __restrict__ imgT, float beta2,
    float* __restrict__ pmin, float* __restrict__ pmax)
{
    __shared__ float twc[256], tws[256];
    __shared__ float invd[256];
    __shared__ __align__(16) float wor[4][256];
    __shared__ float wmn[4], wmx[4];
    fftB_body(Ch, imgT, beta2, pmin, pmax, blockIdx.x, threadIdx.x,
              twc, tws, invd, wor, wmn, wmx);
}

__global__ __launch_bounds__(256) void norm_t(
    const float* __restrict__ imgT, const float* __restrict__ pmin,
    const float* __restrict__ pmax, float* __restrict__ out)
{
    __shared__ float tile[64][65];
    __shared__ float s_mn, s_inv;
    norm_body(imgT, pmin, pmax, out, blockIdx.x, threadIdx.x, 256,
              tile, &s_mn, &s_inv);
}

// ---------- host ----------

static double i0_host(double x) {
    double sum = 1.0, term = 1.0;
    double q = x * x * 0.25;
    for (int k = 1; k < 80; ++k) {
        term *= q / ((double)k * (double)k);
        sum += term;
        if (term < sum * 1e-17) break;
    }
    return sum;
}

extern "C" void kernel_launch(void* const* d_in, const int* in_sizes, int n_in,
                              void* d_out, int out_size, void* d_ws, size_t ws_size,
                              hipStream_t stream)
{
    const float* y_real  = (const float*)d_in[0];
    const float* y_imag  = (const float*)d_in[1];
    const float* weights = (const float*)d_in[2];
    const float2* uv2    = (const float2*)d_in[3];
    float* out = (float*)d_out;

    char* W = (char*)d_ws;
    // Aliased live ranges (peak ~24.4 MB):
    //  W[0,16M): counts[1M] (binning) -> gridh [0,8M) f16 (gather->fftA)
    //            -> imgT [0,2M) (fftB->norm)
    //  A=W+16M:  rec [0,6.4M) + offsets [6.4M,7.45M) (bin->gather)
    //            -> Ch [0,4M) f16 (fftA->fftB); pmin/pmax at [8.4M);
    //            lut at [8.404M); btot at [8.408M)  (btot OUTSIDE gridh range:
    //            gather reads btot while writing gridh)
    h2*       gridh   = (h2*)W;                            // 8 MB (f16 pairs)
    int*      counts  = (int*)W;                           // 1 MB (aliases gridh)
    float*    imgT    = (float*)W;                         // 2 MB (aliases gridh)
    char*     A       = W + (size_t)16 * 1024 * 1024;
    char*     rec     = A;                                 // 6,400,000 B
    int*      offsets = (int*)(A + 6400000);               // 1,048,576 B
    h2*       Ch      = (h2*)A;                            // 4 MB (aliases rec)
    float*    pmin    = (float*)(A + 8400000);             // 2 KB
    float*    pmax    = (float*)(A + 8402048);             // 2 KB
    float*    lut     = (float*)(A + 8404096);             // 4 KB
    int*      btot    = (int*)(A + 8408192);               // 2 KB

    double beta_d = M_PI * sqrt(19.45);   // BETA with alpha=2
    float beta = (float)beta_d;
    float inv_i0b = (float)(1.0 / i0_host(beta_d));
    float beta2 = (float)(beta_d * beta_d);

    hipMemsetAsync(counts, 0, NBINS * sizeof(int), stream);

    count_bins<<<(MPTS + 255) / 256, 256, 0, stream>>>(
        uv2, counts, lut, beta, inv_i0b);

    scan_a<<<512, 512, 0, stream>>>(counts, offsets, btot);

    fill_records<<<(MPTS + 255) / 256, 256, 0, stream>>>(
        uv2, y_real, y_imag, weights, offsets, btot, counts, rec, lut);

    gather_grid<<<2048, 256, 0, stream>>>(offsets, btot, rec, gridh);

    fftA<<<512, 512, 0, stream>>>(gridh, Ch);

    fftB<<<512, 512, 0, stream>>>(Ch, imgT, beta2, pmin, pmax);

    norm_t<<<128, 256, 0, stream>>>(imgT, pmin, pmax, out);
}